// Round 1
// baseline (6494.078 us; speedup 1.0000x reference)
//
#include <hip/hip_runtime.h>
#include <math.h>

#define NN 100000
#define EE 1600000
#define HID 64
#define EDIM 16
#define TDIM 32
// EIN = 2*HID + EDIM + 1 + TDIM = 177 rows of ew1
// NIN = 2*HID + TDIM = 160 rows of nw1

__device__ __forceinline__ float silu_f(float x) {
    // x * sigmoid(x); rcp+exp keep it ~5 VALU instrs, ~1ulp-ish accuracy
    const float e = __expf(-x);
    return x * __builtin_amdgcn_rcpf(1.0f + e);
}

// acc[0..63] += x dot 4 consecutive weight rows (w points at row k, row-major [*,64])
__device__ __forceinline__ void fma4(float* acc, const float4 x, const float* __restrict__ w) {
#pragma unroll
    for (int j = 0; j < HID; ++j)
        acc[j] += x.x * w[j] + x.y * w[HID + j] + x.z * w[2 * HID + j] + x.w * w[3 * HID + j];
}

__global__ void __launch_bounds__(256)
init_kernel(const float* __restrict__ pos, float* __restrict__ m_i,
            float* __restrict__ pos_out)
{
    const int i = blockIdx.x * 256 + threadIdx.x;  // grid covers NN*HID/4 = 1.6M
    const float4 z = make_float4(0.f, 0.f, 0.f, 0.f);
    if (i < NN * HID / 4) reinterpret_cast<float4*>(m_i)[i] = z;
    if (i < NN * 3 / 4)
        reinterpret_cast<float4*>(pos_out)[i] = reinterpret_cast<const float4*>(pos)[i];
}

__global__ void __launch_bounds__(256)
edge_kernel(const float* __restrict__ h, const float* __restrict__ pos,
            const float* __restrict__ ea, const float* __restrict__ te,
            const int* __restrict__ ei,
            const float* __restrict__ ew1, const float* __restrict__ eb1,
            const float* __restrict__ ew2, const float* __restrict__ eb2,
            const float* __restrict__ cw1, const float* __restrict__ cb1,
            const float* __restrict__ cw2,
            float* __restrict__ m_i, float* __restrict__ pos_out)
{
    const int e = blockIdx.x * 256 + threadIdx.x;
    if (e >= EE) return;
    const int row = ei[e];        // edge_index[0, e]  (source)
    const int col = ei[EE + e];   // edge_index[1, e]  (destination / segment id)

    const float rx = pos[3 * row + 0] - pos[3 * col + 0];
    const float ry = pos[3 * row + 1] - pos[3 * col + 1];
    const float rz = pos[3 * row + 2] - pos[3 * col + 2];
    const float dist = sqrtf(rx * rx + ry * ry + rz * rz);

    // ---------- layer 1: edge_input[177] @ ew1 + eb1 ----------
    float acc[HID];
#pragma unroll
    for (int j = 0; j < HID; ++j) acc[j] = eb1[j];

    const float4* hr = reinterpret_cast<const float4*>(h + (size_t)row * HID);
#pragma unroll 1
    for (int c = 0; c < 16; ++c) fma4(acc, hr[c], ew1 + (size_t)(c * 4) * HID);

    const float4* hc = reinterpret_cast<const float4*>(h + (size_t)col * HID);
#pragma unroll 1
    for (int c = 0; c < 16; ++c) fma4(acc, hc[c], ew1 + (size_t)(64 + c * 4) * HID);

    const float4* eav = reinterpret_cast<const float4*>(ea + (size_t)e * EDIM);
#pragma unroll 1
    for (int c = 0; c < 4; ++c) fma4(acc, eav[c], ew1 + (size_t)(128 + c * 4) * HID);

    {   // dist is row 144
        const float* w = ew1 + (size_t)144 * HID;
#pragma unroll
        for (int j = 0; j < HID; ++j) acc[j] += dist * w[j];
    }

    const float4* tev = reinterpret_cast<const float4*>(te + (size_t)row * TDIM);
#pragma unroll 1
    for (int c = 0; c < 8; ++c) fma4(acc, tev[c], ew1 + (size_t)(145 + c * 4) * HID);

    // ---------- silu -> t ----------
    float t[HID];
#pragma unroll
    for (int j = 0; j < HID; ++j) t[j] = silu_f(acc[j]);

    // ---------- layer 2: t @ ew2 + eb2, silu -> m_ij (in t) ----------
    float acc2[HID];
#pragma unroll
    for (int j = 0; j < HID; ++j) acc2[j] = eb2[j];
#pragma unroll
    for (int k = 0; k < HID; ++k) {
        const float x = t[k];
        const float* w = ew2 + (size_t)k * HID;
#pragma unroll
        for (int j = 0; j < HID; ++j) acc2[j] += x * w[j];
    }
#pragma unroll
    for (int j = 0; j < HID; ++j) t[j] = silu_f(acc2[j]);  // t = m_ij

    // ---------- scatter m_ij into m_i[col] (fire-and-forget atomics) ----------
    float* mdst = m_i + (size_t)col * HID;
#pragma unroll
    for (int j = 0; j < HID; ++j) unsafeAtomicAdd(mdst + j, t[j]);

    // ---------- coord MLP: silu(m_ij @ cw1 + cb1) @ cw2 ----------
#pragma unroll
    for (int j = 0; j < HID; ++j) acc2[j] = cb1[j];
#pragma unroll
    for (int k = 0; k < HID; ++k) {
        const float x = t[k];
        const float* w = cw1 + (size_t)k * HID;
#pragma unroll
        for (int j = 0; j < HID; ++j) acc2[j] += x * w[j];
    }
    float cwt = 0.0f;
#pragma unroll
    for (int j = 0; j < HID; ++j) cwt += silu_f(acc2[j]) * cw2[j];

    const float s = cwt / (dist + 1e-8f);
    unsafeAtomicAdd(&pos_out[3 * col + 0], s * rx);
    unsafeAtomicAdd(&pos_out[3 * col + 1], s * ry);
    unsafeAtomicAdd(&pos_out[3 * col + 2], s * rz);
}

__global__ void __launch_bounds__(256)
node_kernel(const float* __restrict__ h, const float* __restrict__ te,
            const float* __restrict__ m_i,
            const float* __restrict__ nw1, const float* __restrict__ nb1,
            const float* __restrict__ nw2, const float* __restrict__ nb2,
            const float* __restrict__ sw, const float* __restrict__ sb,
            const float* __restrict__ tw, const float* __restrict__ tb,
            float* __restrict__ h_out)
{
    const int i = blockIdx.x * 256 + threadIdx.x;
    if (i >= NN) return;

    // ---------- layer 1: [h, m_i, te] @ nw1 + nb1 ----------
    float acc[HID];
#pragma unroll
    for (int j = 0; j < HID; ++j) acc[j] = nb1[j];

    const float4* hv = reinterpret_cast<const float4*>(h + (size_t)i * HID);
#pragma unroll 1
    for (int c = 0; c < 16; ++c) fma4(acc, hv[c], nw1 + (size_t)(c * 4) * HID);
    const float4* mv = reinterpret_cast<const float4*>(m_i + (size_t)i * HID);
#pragma unroll 1
    for (int c = 0; c < 16; ++c) fma4(acc, mv[c], nw1 + (size_t)(64 + c * 4) * HID);
    const float4* tv = reinterpret_cast<const float4*>(te + (size_t)i * TDIM);
#pragma unroll 1
    for (int c = 0; c < 8; ++c) fma4(acc, tv[c], nw1 + (size_t)(128 + c * 4) * HID);

    float t[HID];
#pragma unroll
    for (int j = 0; j < HID; ++j) t[j] = silu_f(acc[j]);

    // ---------- layer 2: t @ nw2 + nb2 -> hu ----------
    float hu[HID];
#pragma unroll
    for (int j = 0; j < HID; ++j) hu[j] = nb2[j];
#pragma unroll
    for (int k = 0; k < HID; ++k) {
        const float x = t[k];
        const float* w = nw2 + (size_t)k * HID;
#pragma unroll
        for (int j = 0; j < HID; ++j) hu[j] += x * w[j];
    }

    // ---------- FiLM scale: te @ sw + sb ----------
#pragma unroll
    for (int j = 0; j < HID; ++j) acc[j] = sb[j];
#pragma unroll 1
    for (int c = 0; c < 8; ++c) fma4(acc, tv[c], sw + (size_t)(c * 4) * HID);
#pragma unroll
    for (int j = 0; j < HID; ++j) hu[j] *= acc[j];

    // ---------- FiLM shift: te @ tw + tb ----------
#pragma unroll
    for (int j = 0; j < HID; ++j) acc[j] = tb[j];
#pragma unroll 1
    for (int c = 0; c < 8; ++c) fma4(acc, tv[c], tw + (size_t)(c * 4) * HID);

    // ---------- h_new = h + scale*hu + shift ----------
    float4* outv = reinterpret_cast<float4*>(h_out + (size_t)i * HID);
#pragma unroll
    for (int c = 0; c < 16; ++c) {
        const float4 hx = hv[c];
        float4 o;
        o.x = hx.x + hu[4 * c + 0] + acc[4 * c + 0];
        o.y = hx.y + hu[4 * c + 1] + acc[4 * c + 1];
        o.z = hx.z + hu[4 * c + 2] + acc[4 * c + 2];
        o.w = hx.w + hu[4 * c + 3] + acc[4 * c + 3];
        outv[c] = o;
    }
}

extern "C" void kernel_launch(void* const* d_in, const int* in_sizes, int n_in,
                              void* d_out, int out_size, void* d_ws, size_t ws_size,
                              hipStream_t stream)
{
    const float* h    = (const float*)d_in[0];
    const float* pos  = (const float*)d_in[1];
    const float* ea   = (const float*)d_in[2];
    const float* te   = (const float*)d_in[3];
    const int*   ei   = (const int*)d_in[4];
    const float* ew1  = (const float*)d_in[5];
    const float* eb1  = (const float*)d_in[6];
    const float* ew2  = (const float*)d_in[7];
    const float* eb2  = (const float*)d_in[8];
    const float* nw1  = (const float*)d_in[9];
    const float* nb1  = (const float*)d_in[10];
    const float* nw2  = (const float*)d_in[11];
    const float* nb2  = (const float*)d_in[12];
    const float* cw1  = (const float*)d_in[13];
    const float* cb1  = (const float*)d_in[14];
    const float* cw2  = (const float*)d_in[15];
    const float* sw   = (const float*)d_in[16];
    const float* sb   = (const float*)d_in[17];
    const float* tw   = (const float*)d_in[18];
    const float* tb   = (const float*)d_in[19];

    float* h_out   = (float*)d_out;                       // [N, 64]
    float* pos_out = (float*)d_out + (size_t)NN * HID;    // [N, 3]
    float* m_i     = (float*)d_ws;                        // [N, 64] scratch accum

    // init: zero m_i, seed pos_out with pos (edge kernel accumulates into it)
    init_kernel<<<(NN * HID / 4 + 255) / 256, 256, 0, stream>>>(pos, m_i, pos_out);

    edge_kernel<<<EE / 256, 256, 0, stream>>>(h, pos, ea, te, ei,
                                              ew1, eb1, ew2, eb2,
                                              cw1, cb1, cw2,
                                              m_i, pos_out);

    node_kernel<<<(NN + 255) / 256, 256, 0, stream>>>(h, te, m_i,
                                                      nw1, nb1, nw2, nb2,
                                                      sw, sb, tw, tb, h_out);
}